// Round 1
// baseline (2634.555 us; speedup 1.0000x reference)
//
#include <hip/hip_runtime.h>

#define EMB 256

// ---------------- DDE: degree counts ----------------
__global__ void k_count(const int* __restrict__ h_id, const int* __restrict__ t_id,
                        float* __restrict__ cnt_f, float* __restrict__ cnt_r, int E) {
  int e = blockIdx.x * 256 + threadIdx.x;
  if (e >= E) return;
  atomicAdd(&cnt_f[t_id[e]], 1.0f);
  atomicAdd(&cnt_r[h_id[e]], 1.0f);
}

// ---------------- DDE: round-1 scatter (fwd + rev) ----------------
__global__ void k_scatter1(const int* __restrict__ h_id, const int* __restrict__ t_id,
                           const float* __restrict__ topic,
                           float* __restrict__ accf, float* __restrict__ accr, int E) {
  int e = blockIdx.x * 256 + threadIdx.x;
  if (e >= E) return;
  int h = h_id[e], t = t_id[e];
  float a0 = topic[2*h+0], a1 = topic[2*h+1];
  if (a0 != 0.f) atomicAdd(&accf[2*t+0], a0);
  if (a1 != 0.f) atomicAdd(&accf[2*t+1], a1);
  float c0 = topic[2*t+0], c1 = topic[2*t+1];
  if (c0 != 0.f) atomicAdd(&accr[2*h+0], c0);
  if (c1 != 0.f) atomicAdd(&accr[2*h+1], c1);
}

// pos layout per node: [topic0,topic1, h1_0,h1_1, h2_0,h2_1, r1_0,r1_1, r2_0,r2_1]
__global__ void k_div1(const float* __restrict__ topic,
                       const float* __restrict__ cnt_f, const float* __restrict__ cnt_r,
                       const float* __restrict__ accf, const float* __restrict__ accr,
                       float* __restrict__ pos, int N) {
  int n = blockIdx.x * 256 + threadIdx.x;
  if (n >= N) return;
  float cf = fmaxf(cnt_f[n], 1.0f), cr = fmaxf(cnt_r[n], 1.0f);
  pos[10*n+0] = topic[2*n+0];
  pos[10*n+1] = topic[2*n+1];
  pos[10*n+2] = accf[2*n+0] / cf;
  pos[10*n+3] = accf[2*n+1] / cf;
  pos[10*n+6] = accr[2*n+0] / cr;
  pos[10*n+7] = accr[2*n+1] / cr;
}

__global__ void k_scatter2(const int* __restrict__ h_id, const int* __restrict__ t_id,
                           const float* __restrict__ pos,
                           float* __restrict__ accf, float* __restrict__ accr, int E) {
  int e = blockIdx.x * 256 + threadIdx.x;
  if (e >= E) return;
  int h = h_id[e], t = t_id[e];
  float a0 = pos[10*h+2], a1 = pos[10*h+3];
  if (a0 != 0.f) atomicAdd(&accf[2*t+0], a0);
  if (a1 != 0.f) atomicAdd(&accf[2*t+1], a1);
  float c0 = pos[10*t+6], c1 = pos[10*t+7];
  if (c0 != 0.f) atomicAdd(&accr[2*h+0], c0);
  if (c1 != 0.f) atomicAdd(&accr[2*h+1], c1);
}

__global__ void k_div2(const float* __restrict__ cnt_f, const float* __restrict__ cnt_r,
                       const float* __restrict__ accf, const float* __restrict__ accr,
                       float* __restrict__ pos, int N) {
  int n = blockIdx.x * 256 + threadIdx.x;
  if (n >= N) return;
  float cf = fmaxf(cnt_f[n], 1.0f), cr = fmaxf(cnt_r[n], 1.0f);
  pos[10*n+4] = accf[2*n+0] / cf;
  pos[10*n+5] = accf[2*n+1] / cf;
  pos[10*n+8] = accr[2*n+0] / cr;
  pos[10*n+9] = accr[2*n+1] / cr;
}

// ---------------- gate softmax + qpart = b1 + q @ W1[:256,:] ----------------
__global__ void k_gate(const float* __restrict__ q, const float* __restrict__ Wg,
                       const float* __restrict__ bg, const float* __restrict__ W1,
                       const float* __restrict__ b1, float* __restrict__ gateq) {
  __shared__ float qs[256];
  __shared__ float z[3];
  int t = threadIdx.x;
  qs[t] = q[t];
  __syncthreads();
  if (t < 3) {
    float s = bg[t];
    for (int k = 0; k < 256; ++k) s += qs[k] * Wg[k*3 + t];
    z[t] = s;
  }
  __syncthreads();
  if (t == 0) {
    float m = fmaxf(z[0], fmaxf(z[1], z[2]));
    float e0 = expf(z[0]-m), e1 = expf(z[1]-m), e2 = expf(z[2]-m);
    float s = e0 + e1 + e2;
    gateq[0] = e0/s; gateq[1] = e1/s; gateq[2] = e2/s; gateq[3] = 0.f;
  }
  float a = b1[t];
  for (int k = 0; k < 256; ++k) a += qs[k] * W1[k*256 + t];
  gateq[4 + t] = a;
}

// ---------------- fused main kernel: 64 edges per block ----------------
// thread t: tc=t&31 -> cols [8tc,8tc+8), tr=t>>5 -> edges [8tr,8tr+8)
__global__ __launch_bounds__(256, 2) void k_main(
    const int* __restrict__ h_id, const int* __restrict__ r_id, const int* __restrict__ t_id,
    const float* __restrict__ ent, const float* __restrict__ ntx,
    const float* __restrict__ rel,
    const int* __restrict__ mids, const float* __restrict__ mwts,
    const float* __restrict__ motif,
    const float* __restrict__ W_nb, const float* __restrict__ b_nb,
    const float* __restrict__ W_pos, const float* __restrict__ b_pos,
    const float* __restrict__ W_str, const float* __restrict__ b_str,
    const float* __restrict__ W1, const float* __restrict__ W2, const float* __restrict__ b2,
    const float* __restrict__ pos, const float* __restrict__ gateq,
    float* __restrict__ out, int E, int NT)
{
  __shared__ __align__(16) float FT[64][264];  // fused [edge][col], padded stride
  __shared__ __align__(16) float XT[32][64];   // K-chunk staging [k][edge]
  __shared__ int hids[64], tids[64], rids[64];
  __shared__ float oacc[64];

  const int t  = threadIdx.x;
  const int tc = t & 31, tr = t >> 5;
  const int col = tc * 8, row = tr * 8;
  const int be = blockIdx.x * 64;
  const int se = t & 63;           // staging edge
  const int sk = (t >> 6) * 8;     // staging k-offset within chunk

  if (t < 64) {
    int e = be + t; if (e >= E) e = E - 1;
    hids[t] = h_id[e]; tids[t] = t_id[e]; rids[t] = r_id[e];
    oacc[t] = 0.f;
  }
  __syncthreads();

  const float g0 = gateq[0], g1 = gateq[1], g2 = gateq[2];

  float fused[8][8];
  float acc[8][8];

  // ===== channel 1: neighbor, X=[h_e[h], h_e[t]], K=512 =====
  #pragma unroll
  for (int i = 0; i < 8; ++i)
    #pragma unroll
    for (int j = 0; j < 8; ++j) acc[i][j] = 0.f;

  for (int k0 = 0; k0 < 512; k0 += 32) {
    {
      int g = k0 + sk;
      int id  = (g < 256) ? hids[se] : tids[se];
      int off = (g < 256) ? g : g - 256;
      const float* src = (id < NT) ? (ent + (size_t)id * EMB + off) : (ntx + off);
      float4 a = ((const float4*)src)[0];
      float4 b = ((const float4*)src)[1];
      XT[sk+0][se] = a.x; XT[sk+1][se] = a.y; XT[sk+2][se] = a.z; XT[sk+3][se] = a.w;
      XT[sk+4][se] = b.x; XT[sk+5][se] = b.y; XT[sk+6][se] = b.z; XT[sk+7][se] = b.w;
    }
    __syncthreads();
    const float* wb = W_nb + (size_t)k0 * 256 + col;
    #pragma unroll 8
    for (int kk = 0; kk < 32; ++kk) {
      const float4* xp = (const float4*)&XT[kk][row];
      float4 x0 = xp[0], x1 = xp[1];
      const float4* wp = (const float4*)(wb + kk * 256);
      float4 w0 = wp[0], w1 = wp[1];
      float xf[8] = {x0.x,x0.y,x0.z,x0.w,x1.x,x1.y,x1.z,x1.w};
      float wf[8] = {w0.x,w0.y,w0.z,w0.w,w1.x,w1.y,w1.z,w1.w};
      #pragma unroll
      for (int i = 0; i < 8; ++i)
        #pragma unroll
        for (int j = 0; j < 8; ++j)
          acc[i][j] = fmaf(xf[i], wf[j], acc[i][j]);
    }
    __syncthreads();
  }
  #pragma unroll
  for (int i = 0; i < 8; ++i)
    #pragma unroll
    for (int j = 0; j < 8; ++j)
      fused[i][j] = g0 * fmaxf(acc[i][j] + b_nb[col+j], 0.f);

  // ===== channel 2: position, X=[pos[h], pos[t]], K=20 =====
  #pragma unroll
  for (int i = 0; i < 8; ++i)
    #pragma unroll
    for (int j = 0; j < 8; ++j) acc[i][j] = 0.f;

  for (int i = t; i < 20*64; i += 256) {
    int kk = i >> 6, e = i & 63;
    float v = (kk < 10) ? pos[(size_t)hids[e]*10 + kk]
                        : pos[(size_t)tids[e]*10 + (kk - 10)];
    XT[kk][e] = v;
  }
  __syncthreads();
  #pragma unroll
  for (int kk = 0; kk < 20; ++kk) {
    const float4* xp = (const float4*)&XT[kk][row];
    float4 x0 = xp[0], x1 = xp[1];
    const float4* wp = (const float4*)(W_pos + (size_t)kk * 256 + col);
    float4 w0 = wp[0], w1 = wp[1];
    float xf[8] = {x0.x,x0.y,x0.z,x0.w,x1.x,x1.y,x1.z,x1.w};
    float wf[8] = {w0.x,w0.y,w0.z,w0.w,w1.x,w1.y,w1.z,w1.w};
    #pragma unroll
    for (int i = 0; i < 8; ++i)
      #pragma unroll
      for (int j = 0; j < 8; ++j)
        acc[i][j] = fmaf(xf[i], wf[j], acc[i][j]);
  }
  __syncthreads();
  #pragma unroll
  for (int i = 0; i < 8; ++i)
    #pragma unroll
    for (int j = 0; j < 8; ++j)
      fused[i][j] += g1 * fmaxf(acc[i][j] + b_pos[col+j], 0.f);

  // ===== channel 3: struct, X=[rel[r], triple_motif], K=320 =====
  #pragma unroll
  for (int i = 0; i < 8; ++i)
    #pragma unroll
    for (int j = 0; j < 8; ++j) acc[i][j] = 0.f;

  for (int k0 = 0; k0 < 320; k0 += 32) {
    int g = k0 + sk;
    if (g < 256) {
      const float* src = rel + (size_t)rids[se] * EMB + g;
      float4 a = ((const float4*)src)[0];
      float4 b = ((const float4*)src)[1];
      XT[sk+0][se] = a.x; XT[sk+1][se] = a.y; XT[sk+2][se] = a.z; XT[sk+3][se] = a.w;
      XT[sk+4][se] = b.x; XT[sk+5][se] = b.y; XT[sk+6][se] = b.z; XT[sk+7][se] = b.w;
    } else {
      int d0 = g - 256;                     // 0..56
      int e = be + se; if (e >= E) e = E - 1;
      const int*   ip  = mids + (size_t)e * 8;
      const float* wpp = mwts + (size_t)e * 8;
      float s[8] = {0,0,0,0,0,0,0,0};
      #pragma unroll
      for (int l = 0; l < 8; ++l) {
        int id = ip[l];
        float w = wpp[l];
        if (id != 0) {                      // padding_idx=0 -> zero row
          const float* mr = motif + id * 64 + d0;
          #pragma unroll
          for (int i = 0; i < 8; ++i) s[i] = fmaf(mr[i], w, s[i]);
        }
      }
      #pragma unroll
      for (int i = 0; i < 8; ++i) XT[sk+i][se] = s[i];
    }
    __syncthreads();
    const float* wb = W_str + (size_t)k0 * 256 + col;
    #pragma unroll 8
    for (int kk = 0; kk < 32; ++kk) {
      const float4* xp = (const float4*)&XT[kk][row];
      float4 x0 = xp[0], x1 = xp[1];
      const float4* wp = (const float4*)(wb + kk * 256);
      float4 w0 = wp[0], w1 = wp[1];
      float xf[8] = {x0.x,x0.y,x0.z,x0.w,x1.x,x1.y,x1.z,x1.w};
      float wf[8] = {w0.x,w0.y,w0.z,w0.w,w1.x,w1.y,w1.z,w1.w};
      #pragma unroll
      for (int i = 0; i < 8; ++i)
        #pragma unroll
        for (int j = 0; j < 8; ++j)
          acc[i][j] = fmaf(xf[i], wf[j], acc[i][j]);
    }
    __syncthreads();
  }
  #pragma unroll
  for (int i = 0; i < 8; ++i)
    #pragma unroll
    for (int j = 0; j < 8; ++j)
      fused[i][j] += g2 * fmaxf(acc[i][j] + b_str[col+j], 0.f);

  // ===== stage fused to LDS (FT[edge][col]) =====
  #pragma unroll
  for (int i = 0; i < 8; ++i) {
    float4* fp = (float4*)&FT[row+i][col];
    fp[0] = make_float4(fused[i][0], fused[i][1], fused[i][2], fused[i][3]);
    fp[1] = make_float4(fused[i][4], fused[i][5], fused[i][6], fused[i][7]);
  }
  __syncthreads();

  // ===== layer 1: acc = qpart + fused @ W1[256:,:], K=256 =====
  {
    const float4* qp = (const float4*)(gateq + 4 + col);
    float4 q0 = qp[0], q1 = qp[1];
    float qv[8] = {q0.x,q0.y,q0.z,q0.w,q1.x,q1.y,q1.z,q1.w};
    #pragma unroll
    for (int i = 0; i < 8; ++i)
      #pragma unroll
      for (int j = 0; j < 8; ++j) acc[i][j] = qv[j];
  }
  #pragma unroll 4
  for (int kk = 0; kk < 256; kk += 2) {
    const float* wb = W1 + (size_t)(256 + kk) * 256 + col;
    float4 w0 = ((const float4*)wb)[0], w1 = ((const float4*)wb)[1];
    float4 v0 = ((const float4*)(wb + 256))[0], v1 = ((const float4*)(wb + 256))[1];
    float wf0[8] = {w0.x,w0.y,w0.z,w0.w,w1.x,w1.y,w1.z,w1.w};
    float wf1[8] = {v0.x,v0.y,v0.z,v0.w,v1.x,v1.y,v1.z,v1.w};
    float2 xf[8];
    #pragma unroll
    for (int i = 0; i < 8; ++i) xf[i] = *(const float2*)&FT[row+i][kk];
    #pragma unroll
    for (int i = 0; i < 8; ++i)
      #pragma unroll
      for (int j = 0; j < 8; ++j) {
        acc[i][j] = fmaf(xf[i].x, wf0[j], acc[i][j]);
        acc[i][j] = fmaf(xf[i].y, wf1[j], acc[i][j]);
      }
  }

  // ===== layer 2: out = relu(act) @ W2 + b2 =====
  {
    const float4* w2p = (const float4*)(W2 + col);
    float4 w20 = w2p[0], w21 = w2p[1];
    float w2f[8] = {w20.x,w20.y,w20.z,w20.w,w21.x,w21.y,w21.z,w21.w};
    #pragma unroll
    for (int i = 0; i < 8; ++i) {
      float p = 0.f;
      #pragma unroll
      for (int j = 0; j < 8; ++j)
        p = fmaf(fmaxf(acc[i][j], 0.f), w2f[j], p);
      atomicAdd(&oacc[row+i], p);
    }
  }
  __syncthreads();
  if (t < 64) {
    int e = be + t;
    if (e < E) out[e] = oacc[t] + b2[0];
  }
}

extern "C" void kernel_launch(void* const* d_in, const int* in_sizes, int n_in,
                              void* d_out, int out_size, void* d_ws, size_t ws_size,
                              hipStream_t stream) {
  const int*   h_id  = (const int*)  d_in[0];
  const int*   r_id  = (const int*)  d_in[1];
  const int*   t_id  = (const int*)  d_in[2];
  const float* q     = (const float*)d_in[3];
  const float* ent   = (const float*)d_in[4];
  const float* rel   = (const float*)d_in[6];
  const float* topic = (const float*)d_in[7];
  const int*   mids  = (const int*)  d_in[8];
  const float* mwts  = (const float*)d_in[9];
  const float* ntx   = (const float*)d_in[10];
  const float* motif = (const float*)d_in[11];
  const float* W_nb  = (const float*)d_in[12];
  const float* b_nb  = (const float*)d_in[13];
  const float* W_pos = (const float*)d_in[14];
  const float* b_pos = (const float*)d_in[15];
  const float* W_str = (const float*)d_in[16];
  const float* b_str = (const float*)d_in[17];
  const float* W_g   = (const float*)d_in[18];
  const float* b_g   = (const float*)d_in[19];
  const float* W1    = (const float*)d_in[20];
  const float* b1    = (const float*)d_in[21];
  const float* W2    = (const float*)d_in[22];
  const float* b2    = (const float*)d_in[23];
  float* out = (float*)d_out;

  const int E  = in_sizes[0];
  const int NT = in_sizes[4] / EMB;   // 80000 text entities
  const int N  = in_sizes[7] / 2;     // 100000 total nodes

  float* ws    = (float*)d_ws;
  float* cnt_f = ws;
  float* cnt_r = ws + (size_t)N;
  float* a1f   = ws + (size_t)2*N;
  float* a1r   = ws + (size_t)4*N;
  float* a2f   = ws + (size_t)6*N;
  float* a2r   = ws + (size_t)8*N;
  float* pos   = ws + (size_t)10*N;   // N x 10
  float* gateq = ws + (size_t)20*N;   // [g0,g1,g2,pad, qpart(256)]

  hipMemsetAsync(d_ws, 0, (size_t)10 * N * sizeof(float), stream);

  int gE = (E + 255) / 256, gN = (N + 255) / 256;
  k_count   <<<gE, 256, 0, stream>>>(h_id, t_id, cnt_f, cnt_r, E);
  k_scatter1<<<gE, 256, 0, stream>>>(h_id, t_id, topic, a1f, a1r, E);
  k_div1    <<<gN, 256, 0, stream>>>(topic, cnt_f, cnt_r, a1f, a1r, pos, N);
  k_scatter2<<<gE, 256, 0, stream>>>(h_id, t_id, pos, a2f, a2r, E);
  k_div2    <<<gN, 256, 0, stream>>>(cnt_f, cnt_r, a2f, a2r, pos, N);
  k_gate    <<<1, 256, 0, stream>>>(q, W_g, b_g, W1, b1, gateq);

  int gM = (E + 63) / 64;
  k_main<<<gM, 256, 0, stream>>>(h_id, r_id, t_id, ent, ntx, rel, mids, mwts, motif,
                                 W_nb, b_nb, W_pos, b_pos, W_str, b_str, W1, W2, b2,
                                 pos, gateq, out, E, NT);
}

// Round 2
// 654.011 us; speedup vs baseline: 4.0283x; 4.0283x over previous
//
#include <hip/hip_runtime.h>

#define EMB 256
typedef unsigned short u16;
typedef __attribute__((ext_vector_type(8))) short short8v;
typedef __attribute__((ext_vector_type(4))) float f32x4;

__device__ inline u16 f2bf(float x){
  union{float f; unsigned u;} c; c.f = x;
  unsigned r = c.u + 0x7FFFu + ((c.u>>16)&1u);
  return (u16)(r>>16);
}

__device__ inline short8v pack8(float4 a, float4 b){
  short8v v;
  v[0]=(short)f2bf(a.x); v[1]=(short)f2bf(a.y); v[2]=(short)f2bf(a.z); v[3]=(short)f2bf(a.w);
  v[4]=(short)f2bf(b.x); v[5]=(short)f2bf(b.y); v[6]=(short)f2bf(b.z); v[7]=(short)f2bf(b.w);
  return v;
}

// ---------------- DDE: degree counts ----------------
__global__ void k_count(const int* __restrict__ h_id, const int* __restrict__ t_id,
                        float* __restrict__ cnt_f, float* __restrict__ cnt_r, int E) {
  int e = blockIdx.x * 256 + threadIdx.x;
  if (e >= E) return;
  atomicAdd(&cnt_f[t_id[e]], 1.0f);
  atomicAdd(&cnt_r[h_id[e]], 1.0f);
}

__global__ void k_scatter1(const int* __restrict__ h_id, const int* __restrict__ t_id,
                           const float* __restrict__ topic,
                           float* __restrict__ accf, float* __restrict__ accr, int E) {
  int e = blockIdx.x * 256 + threadIdx.x;
  if (e >= E) return;
  int h = h_id[e], t = t_id[e];
  float a0 = topic[2*h+0], a1 = topic[2*h+1];
  if (a0 != 0.f) atomicAdd(&accf[2*t+0], a0);
  if (a1 != 0.f) atomicAdd(&accf[2*t+1], a1);
  float c0 = topic[2*t+0], c1 = topic[2*t+1];
  if (c0 != 0.f) atomicAdd(&accr[2*h+0], c0);
  if (c1 != 0.f) atomicAdd(&accr[2*h+1], c1);
}

__global__ void k_div1(const float* __restrict__ topic,
                       const float* __restrict__ cnt_f, const float* __restrict__ cnt_r,
                       const float* __restrict__ accf, const float* __restrict__ accr,
                       float* __restrict__ pos, int N) {
  int n = blockIdx.x * 256 + threadIdx.x;
  if (n >= N) return;
  float cf = fmaxf(cnt_f[n], 1.0f), cr = fmaxf(cnt_r[n], 1.0f);
  pos[10*n+0] = topic[2*n+0];
  pos[10*n+1] = topic[2*n+1];
  pos[10*n+2] = accf[2*n+0] / cf;
  pos[10*n+3] = accf[2*n+1] / cf;
  pos[10*n+6] = accr[2*n+0] / cr;
  pos[10*n+7] = accr[2*n+1] / cr;
}

__global__ void k_scatter2(const int* __restrict__ h_id, const int* __restrict__ t_id,
                           const float* __restrict__ pos,
                           float* __restrict__ accf, float* __restrict__ accr, int E) {
  int e = blockIdx.x * 256 + threadIdx.x;
  if (e >= E) return;
  int h = h_id[e], t = t_id[e];
  float a0 = pos[10*h+2], a1 = pos[10*h+3];
  if (a0 != 0.f) atomicAdd(&accf[2*t+0], a0);
  if (a1 != 0.f) atomicAdd(&accf[2*t+1], a1);
  float c0 = pos[10*t+6], c1 = pos[10*t+7];
  if (c0 != 0.f) atomicAdd(&accr[2*h+0], c0);
  if (c1 != 0.f) atomicAdd(&accr[2*h+1], c1);
}

__global__ void k_div2(const float* __restrict__ cnt_f, const float* __restrict__ cnt_r,
                       const float* __restrict__ accf, const float* __restrict__ accr,
                       float* __restrict__ pos, int N) {
  int n = blockIdx.x * 256 + threadIdx.x;
  if (n >= N) return;
  float cf = fmaxf(cnt_f[n], 1.0f), cr = fmaxf(cnt_r[n], 1.0f);
  pos[10*n+4] = accf[2*n+0] / cf;
  pos[10*n+5] = accf[2*n+1] / cf;
  pos[10*n+8] = accr[2*n+0] / cr;
  pos[10*n+9] = accr[2*n+1] / cr;
}

// ---------------- gate softmax + qpart = b1 + q @ W1[:256,:] ----------------
__global__ void k_gate(const float* __restrict__ q, const float* __restrict__ Wg,
                       const float* __restrict__ bg, const float* __restrict__ W1,
                       const float* __restrict__ b1, float* __restrict__ gateq) {
  __shared__ float qs[256];
  __shared__ float z[3];
  int t = threadIdx.x;
  qs[t] = q[t];
  __syncthreads();
  if (t < 3) {
    float s = bg[t];
    for (int k = 0; k < 256; ++k) s += qs[k] * Wg[k*3 + t];
    z[t] = s;
  }
  __syncthreads();
  if (t == 0) {
    float m = fmaxf(z[0], fmaxf(z[1], z[2]));
    float e0 = expf(z[0]-m), e1 = expf(z[1]-m), e2 = expf(z[2]-m);
    float s = e0 + e1 + e2;
    gateq[0] = e0/s; gateq[1] = e1/s; gateq[2] = e2/s; gateq[3] = 0.f;
  }
  float a = b1[t];
  for (int k = 0; k < 256; ++k) a += qs[k] * W1[k*256 + t];
  gateq[4 + t] = a;
}

// ---------------- weight transform: MFMA B-fragment layout, bf16 ----------------
// 35 kt-chunks of K=32: [0..15]=W_nb(512), [16]=W_pos(20,zero-pad),
// [17..26]=W_str(320), [27..34]=W1[256:512]. Frag order: ((kt*16+nt)*64+lane)*8.
__global__ void k_wtrans(const float* __restrict__ Wnb, const float* __restrict__ Wpos,
                         const float* __restrict__ Wstr, const float* __restrict__ W1,
                         u16* __restrict__ WB) {
  int gid = blockIdx.x * 256 + threadIdx.x;
  if (gid >= 35*16*64) return;
  int lane = gid & 63;
  int nt   = (gid >> 6) & 15;
  int kt   = gid >> 10;
  const float* src; int kbase, klim;
  if (kt < 16)      { src = Wnb;               kbase = kt*32;      klim = 512; }
  else if (kt==16)  { src = Wpos;              kbase = 0;          klim = 20;  }
  else if (kt < 27) { src = Wstr;              kbase = (kt-17)*32; klim = 320; }
  else              { src = W1 + 256*256;      kbase = (kt-27)*32; klim = 256; }
  int n  = nt*16 + (lane & 15);
  int k0 = kbase + (lane >> 4) * 8;
  short8v v;
  #pragma unroll
  for (int j = 0; j < 8; ++j) {
    int k = k0 + j;
    v[j] = (k < klim) ? (short)f2bf(src[(size_t)k*256 + n]) : (short)0;
  }
  *(short8v*)(WB + (size_t)gid * 8) = v;
}

// ---------------- fused MFMA main kernel: 128 edges/block, 8 waves ----------------
__global__ __launch_bounds__(512, 2) void k_main(
    const int* __restrict__ h_id, const int* __restrict__ r_id, const int* __restrict__ t_id,
    const float* __restrict__ ent, const float* __restrict__ ntx,
    const float* __restrict__ rel,
    const int* __restrict__ mids, const float* __restrict__ mwts,
    const float* __restrict__ motif,
    const float* __restrict__ b_nb, const float* __restrict__ b_pos, const float* __restrict__ b_str,
    const float* __restrict__ W2, const float* __restrict__ b2,
    const float* __restrict__ pos, const float* __restrict__ gateq,
    const u16* __restrict__ WBg,
    float* __restrict__ out, int E, int NT)
{
  __shared__ __align__(16) u16 XA[128*256];   // A tile, bf16, XOR unit-swizzled (64 KB)
  __shared__ __align__(16) u16 Bb[8192];      // one B chunk: 16 nt x 64 lanes x 8 bf16 (16 KB)
  __shared__ int hids[128], tids[128], rids[128];
  __shared__ float oacc[128];

  const int t  = threadIdx.x;
  const int w  = t >> 6, l = t & 63;
  const int Mw = w >> 2, Nw = w & 3;
  const int lr = l & 15, lg = l >> 4;
  const int rowbase = Mw * 64, colbase = Nw * 64;
  const int be = blockIdx.x * 128;

  if (t < 128) {
    int e = be + t; if (e >= E) e = E - 1;
    hids[t] = h_id[e]; tids[t] = t_id[e]; rids[t] = r_id[e];
    oacc[t] = 0.f;
  }
  __syncthreads();

  const float g0 = gateq[0], g1 = gateq[1], g2 = gateq[2];

  f32x4 acc[4][4];
  float fused[4][4][4];

  auto zacc = [&]() {
    #pragma unroll
    for (int m = 0; m < 4; ++m)
      #pragma unroll
      for (int n = 0; n < 4; ++n)
        acc[m][n] = (f32x4){0.f, 0.f, 0.f, 0.f};
  };

  // stage one 256-f32 gathered row set into XA (8 units of 8 bf16 per thread)
  auto stage_rows = [&](const int* ids, const float* table, bool clampNT) {
    int r = t >> 2, p = t & 3;
    int id = ids[r];
    const float* src = (clampNT && id >= NT) ? ntx : (table + (size_t)id * EMB);
    #pragma unroll
    for (int i = 0; i < 8; ++i) {
      int u = p * 8 + i;
      float4 a = *(const float4*)(src + u*8);
      float4 b = *(const float4*)(src + u*8 + 4);
      *(short8v*)&XA[r*256 + ((u ^ (r & 7)) << 3)] = pack8(a, b);
    }
  };

  // one GEMM phase: nch chunks of K=32 starting at global WB chunk ktbase
  auto phase = [&](int ktbase, int nch) {
    { // prologue: chunk 0
      const uint4* g = (const uint4*)(WBg + (size_t)ktbase * 8192);
      uint4 p0 = g[t*2], p1 = g[t*2 + 1];
      *(uint4*)&Bb[t*16] = p0; *(uint4*)&Bb[t*16 + 8] = p1;
    }
    __syncthreads();
    for (int c = 0; c < nch; ++c) {
      uint4 p0, p1;
      bool pf = (c + 1 < nch);
      if (pf) {
        const uint4* g = (const uint4*)(WBg + (size_t)(ktbase + c + 1) * 8192);
        p0 = g[t*2]; p1 = g[t*2 + 1];
      }
      short8v bfr[4];
      #pragma unroll
      for (int n = 0; n < 4; ++n)
        bfr[n] = *(const short8v*)&Bb[((Nw*4 + n)*64 + l) * 8];
      #pragma unroll
      for (int m = 0; m < 4; ++m) {
        int row = rowbase + m*16 + lr;
        int u = (c*4 + lg) ^ (lr & 7);
        short8v af = *(const short8v*)&XA[row*256 + u*8];
        #pragma unroll
        for (int n = 0; n < 4; ++n)
          acc[m][n] = __builtin_amdgcn_mfma_f32_16x16x32_bf16(af, bfr[n], acc[m][n], 0, 0, 0);
      }
      __syncthreads();
      if (pf) { *(uint4*)&Bb[t*16] = p0; *(uint4*)&Bb[t*16 + 8] = p1; }
      __syncthreads();
    }
  };

  auto combine = [&](const float* bias, float g, bool first) {
    #pragma unroll
    for (int n = 0; n < 4; ++n) {
      float bv = bias[colbase + n*16 + lr];
      #pragma unroll
      for (int m = 0; m < 4; ++m)
        #pragma unroll
        for (int r2 = 0; r2 < 4; ++r2) {
          float val = fmaxf(acc[m][n][r2] + bv, 0.f) * g;
          if (first) fused[m][n][r2] = val; else fused[m][n][r2] += val;
        }
    }
  };

  // ===== channel 1: neighbor (h rows then t rows, K=512) =====
  zacc();
  stage_rows(hids, ent, true);
  phase(0, 8);
  stage_rows(tids, ent, true);
  phase(8, 8);
  combine(b_nb, g0, true);

  // ===== channel 2: position (K=20 padded to 32) =====
  zacc();
  {
    int r = t >> 2, p = t & 3;
    float vals[8];
    #pragma unroll
    for (int j = 0; j < 8; ++j) {
      int k = p*8 + j;
      vals[j] = (k < 10) ? pos[(size_t)hids[r]*10 + k]
              : (k < 20) ? pos[(size_t)tids[r]*10 + (k - 10)] : 0.f;
    }
    short8v v;
    #pragma unroll
    for (int j = 0; j < 8; ++j) v[j] = (short)f2bf(vals[j]);
    *(short8v*)&XA[r*256 + ((p ^ (r & 7)) << 3)] = v;
  }
  phase(16, 1);
  combine(b_pos, g1, false);

  // ===== channel 3: struct (rel rows K=256, then motif K=64) =====
  zacc();
  stage_rows(rids, rel, false);
  phase(17, 8);
  {
    int r = t >> 2, p = t & 3;
    int e = be + r; if (e >= E) e = E - 1;
    int ids8[8]; float ws8[8];
    #pragma unroll
    for (int j = 0; j < 8; ++j) { ids8[j] = mids[(size_t)e*8 + j]; ws8[j] = mwts[(size_t)e*8 + j]; }
    #pragma unroll
    for (int half = 0; half < 2; ++half) {
      int u = p + half*4;               // dims [u*8, u*8+8)
      float s[8] = {0,0,0,0,0,0,0,0};
      #pragma unroll
      for (int j = 0; j < 8; ++j) {
        if (ids8[j] != 0) {
          const float* mr = motif + (size_t)ids8[j]*64 + u*8;
          #pragma unroll
          for (int i = 0; i < 8; ++i) s[i] = fmaf(mr[i], ws8[j], s[i]);
        }
      }
      short8v v;
      #pragma unroll
      for (int i = 0; i < 8; ++i) v[i] = (short)f2bf(s[i]);
      *(short8v*)&XA[r*256 + ((u ^ (r & 7)) << 3)] = v;
    }
  }
  phase(25, 2);
  combine(b_str, g2, false);

  // ===== stage fused -> XA (bf16), layer 1 =====
  #pragma unroll
  for (int m = 0; m < 4; ++m)
    #pragma unroll
    for (int r2 = 0; r2 < 4; ++r2) {
      int row = rowbase + m*16 + lg*4 + r2;
      #pragma unroll
      for (int n = 0; n < 4; ++n) {
        int col = colbase + n*16 + lr;
        int u = (col >> 3) ^ (row & 7);
        XA[row*256 + u*8 + (col & 7)] = f2bf(fused[m][n][r2]);
      }
    }
  // init acc with qpart (b1 + q@W1_top), broadcast along rows
  #pragma unroll
  for (int n = 0; n < 4; ++n) {
    float qv = gateq[4 + colbase + n*16 + lr];
    #pragma unroll
    for (int m = 0; m < 4; ++m) acc[m][n] = (f32x4){qv, qv, qv, qv};
  }
  phase(27, 8);

  // ===== layer 2: out = relu(act) @ W2 + b2 =====
  {
    float w2v[4];
    #pragma unroll
    for (int n = 0; n < 4; ++n) w2v[n] = W2[colbase + n*16 + lr];
    #pragma unroll
    for (int m = 0; m < 4; ++m)
      #pragma unroll
      for (int r2 = 0; r2 < 4; ++r2) {
        float p = 0.f;
        #pragma unroll
        for (int n = 0; n < 4; ++n) p = fmaf(fmaxf(acc[m][n][r2], 0.f), w2v[n], p);
        p += __shfl_xor(p, 1); p += __shfl_xor(p, 2);
        p += __shfl_xor(p, 4); p += __shfl_xor(p, 8);
        if (lr == 0) atomicAdd(&oacc[rowbase + m*16 + lg*4 + r2], p);
      }
  }
  __syncthreads();
  if (t < 128) {
    int e = be + t;
    if (e < E) out[e] = oacc[t] + b2[0];
  }
}

extern "C" void kernel_launch(void* const* d_in, const int* in_sizes, int n_in,
                              void* d_out, int out_size, void* d_ws, size_t ws_size,
                              hipStream_t stream) {
  const int*   h_id  = (const int*)  d_in[0];
  const int*   r_id  = (const int*)  d_in[1];
  const int*   t_id  = (const int*)  d_in[2];
  const float* q     = (const float*)d_in[3];
  const float* ent   = (const float*)d_in[4];
  const float* rel   = (const float*)d_in[6];
  const float* topic = (const float*)d_in[7];
  const int*   mids  = (const int*)  d_in[8];
  const float* mwts  = (const float*)d_in[9];
  const float* ntx   = (const float*)d_in[10];
  const float* motif = (const float*)d_in[11];
  const float* W_nb  = (const float*)d_in[12];
  const float* b_nb  = (const float*)d_in[13];
  const float* W_pos = (const float*)d_in[14];
  const float* b_pos = (const float*)d_in[15];
  const float* W_str = (const float*)d_in[16];
  const float* b_str = (const float*)d_in[17];
  const float* W_g   = (const float*)d_in[18];
  const float* b_g   = (const float*)d_in[19];
  const float* W1    = (const float*)d_in[20];
  const float* b1    = (const float*)d_in[21];
  const float* W2    = (const float*)d_in[22];
  const float* b2    = (const float*)d_in[23];
  float* out = (float*)d_out;

  const int E  = in_sizes[0];
  const int NT = in_sizes[4] / EMB;   // 80000 text entities
  const int N  = in_sizes[7] / 2;     // 100000 total nodes

  float* ws    = (float*)d_ws;
  float* cnt_f = ws;
  float* cnt_r = ws + (size_t)N;
  float* a1f   = ws + (size_t)2*N;
  float* a1r   = ws + (size_t)4*N;
  float* a2f   = ws + (size_t)6*N;
  float* a2r   = ws + (size_t)8*N;
  float* pos   = ws + (size_t)10*N;   // N x 10
  float* gateq = ws + (size_t)20*N;   // [g0,g1,g2,pad, qpart(256)]
  u16*   WBg   = (u16*)(ws + (size_t)20*N + 512);  // 35 chunks x 16KB bf16 frags

  hipMemsetAsync(d_ws, 0, (size_t)10 * N * sizeof(float), stream);

  int gE = (E + 255) / 256, gN = (N + 255) / 256;
  k_count   <<<gE, 256, 0, stream>>>(h_id, t_id, cnt_f, cnt_r, E);
  k_scatter1<<<gE, 256, 0, stream>>>(h_id, t_id, topic, a1f, a1r, E);
  k_div1    <<<gN, 256, 0, stream>>>(topic, cnt_f, cnt_r, a1f, a1r, pos, N);
  k_scatter2<<<gE, 256, 0, stream>>>(h_id, t_id, pos, a2f, a2r, E);
  k_div2    <<<gN, 256, 0, stream>>>(cnt_f, cnt_r, a2f, a2r, pos, N);
  k_gate    <<<1, 256, 0, stream>>>(q, W_g, b_g, W1, b1, gateq);
  k_wtrans  <<<140, 256, 0, stream>>>(W_nb, W_pos, W_str, W1, (u16*)WBg);

  int gM = (E + 127) / 128;
  k_main<<<gM, 512, 0, stream>>>(h_id, r_id, t_id, ent, ntx, rel, mids, mwts, motif,
                                 b_nb, b_pos, b_str, W2, b2,
                                 pos, gateq, WBg, out, E, NT);
}